// Round 17
// baseline (715.392 us; speedup 1.0000x reference)
//
#include <hip/hip_runtime.h>
#include <cmath>

#define B_   128
#define N_   39
#define KNN_ 10
#define H_   256
#define K1_  32
#define K2_  26
#define K3_  21

static inline int cdiv(int a, int b) { return (a + b - 1) / b; }

typedef __attribute__((ext_vector_type(8))) short short8;
typedef __attribute__((ext_vector_type(4))) short short4v;
typedef __attribute__((ext_vector_type(4))) float floatx4;

__device__ inline short f2b(float f) {   // fp32 -> bf16 RNE
  unsigned u = __float_as_uint(f);
  u += 0x7fff + ((u >> 16) & 1);
  return (short)(u >> 16);
}
__device__ inline float b2f(short h) {
  return __uint_as_float(((unsigned)(unsigned short)h) << 16);
}
__device__ inline void f2b3(float v, short& h, short& m, short& l) {  // v ~= h+m+l (24 bits)
  h = f2b(v);
  float r1 = v - b2f(h);
  m = f2b(r1);
  l = f2b(r1 - b2f(m));
}

// ------------- one-shot prep: weights triple-split transposed + x split + degree -------------
__global__ void prep_kernel(
    const float* __restrict__ w1, const float* __restrict__ w2,
    const float* __restrict__ w3, const float* __restrict__ w6,
    const float* __restrict__ l4, const float* __restrict__ l5,
    const float* __restrict__ x, const float* __restrict__ adj,
    short* __restrict__ wt1h, short* __restrict__ wt1m, short* __restrict__ wt1l,
    short* __restrict__ wt2h, short* __restrict__ wt2m, short* __restrict__ wt2l,
    short* __restrict__ wt3h, short* __restrict__ wt3m, short* __restrict__ wt3l,
    short* __restrict__ wt6h, short* __restrict__ wt6m,
    short* __restrict__ l4h, short* __restrict__ l4m,
    short* __restrict__ l5h, short* __restrict__ l5m,
    short* __restrict__ xsph, short* __restrict__ xspm, short* __restrict__ xspl,
    float* __restrict__ deg) {
  int task = blockIdx.y;
  int t = blockIdx.x * 256 + threadIdx.x;
  if (task == 0) {            // wcat1 tripleT: [512][64], K=39 padded
    if (t >= 512 * 64) return;
    int nn = t >> 6, k = t & 63;
    float v = 0.f;
    if (k < 39) v = (nn < 256) ? w1[k * 256 + nn] - w1[(39 + k) * 256 + nn]
                               : w1[(39 + k) * 256 + (nn - 256)];
    short h, m, l; f2b3(v, h, m, l);
    wt1h[t] = h; wt1m[t] = m; wt1l[t] = l;
  } else if (task == 1) {     // wcat2 tripleT: [512][256]
    if (t >= 512 * 256) return;
    int nn = t >> 8, k = t & 255;
    float v = (nn < 256) ? w2[k * 256 + nn] - w2[(256 + k) * 256 + nn]
                         : w2[(256 + k) * 256 + (nn - 256)];
    short h, m, l; f2b3(v, h, m, l);
    wt2h[t] = h; wt2m[t] = m; wt2l[t] = l;
  } else if (task == 2) {     // wcat3 tripleT
    if (t >= 512 * 256) return;
    int nn = t >> 8, k = t & 255;
    float v = (nn < 256) ? w3[k * 256 + nn] - w3[(256 + k) * 256 + nn]
                         : w3[(256 + k) * 256 + (nn - 256)];
    short h, m, l; f2b3(v, h, m, l);
    wt3h[t] = h; wt3m[t] = m; wt3l[t] = l;
  } else if (task == 3) {     // wcat6 T (h,m): [78][256]
    if (t >= 78 * 256) return;
    int nn = t >> 8, k = t & 255;
    float v = (nn < 39) ? w6[k * 39 + nn] - w6[(256 + k) * 39 + nn]
                        : w6[(256 + k) * 39 + (nn - 39)];
    short h, m, l; f2b3(v, h, m, l);
    wt6h[t] = h; wt6m[t] = m;
  } else if (task == 4) {     // lin4 T (h,m): [256][256]
    if (t >= 256 * 256) return;
    int nn = t >> 8, k = t & 255;
    short h, m, l; f2b3(l4[k * 256 + nn], h, m, l);
    l4h[t] = h; l4m[t] = m;
  } else if (task == 5) {     // lin5 T (h,m): [128][256]
    if (t >= 128 * 256) return;
    int nn = t >> 8, k = t & 255;
    short h, m, l; f2b3(l5[k * 128 + nn], h, m, l);
    l5h[t] = h; l5m[t] = m;
  } else if (task == 6) {     // x split: [4992][64], F=39 padded
    if (t >= 4992 * 64) return;
    int r = t >> 6, k = t & 63;
    float v = (k < 39) ? x[r * 39 + k] : 0.f;
    short h, m, l; f2b3(v, h, m, l);
    xsph[t] = h; xspm[t] = m; xspl[t] = l;
  } else {                    // degree
    if (t >= B_ * N_) return;
    const float* row = adj + (size_t)t * N_;
    float s = 0.f;
    for (int j = 0; j < N_; ++j) s += row[j];
    deg[t] = s;
  }
}

// ======== fused KNN + GEMM (one dispatch; block role by blockIdx.x) ========
// knn: blocks [0, knnB): MFMA gram + rank-parallel KNN (per graph).
// gemm: blocks [knnB, ...): C = A·W^T, M%128==0; store guard on N. Both 512 thr.
// Register-prefetch software pipeline: chunk k+1's global loads issued right
// after the sync, overlapping chunk k's MFMA compute. MFMA order fixed.
__global__ __launch_bounds__(512) void knn_gemm_kernel(
    const short* __restrict__ kxh, const short* __restrict__ kxm, const short* __restrict__ kxl,
    int knt, int kKs, int kn, int kF32, int* __restrict__ idx, int knnB,
    const short* __restrict__ Ah, const short* __restrict__ Am, const short* __restrict__ Al,
    int gnt, int gK,
    const short* __restrict__ Wh, const short* __restrict__ Wm, const short* __restrict__ Wl,
    float* __restrict__ C0, int gM, int gN, int gyB,
    size_t Astride, size_t Cstride) {
  extern __shared__ char smem[];
  int tid = threadIdx.x;
  int wave = tid >> 6, lane = tid & 63;
  int lm = lane & 15, lk = (lane >> 4) * 8;
  if ((int)blockIdx.x < knnB) {
    // ---------------- KNN path ----------------
    short* sh_h = (short*)smem;
    short* sh_m = sh_h + 48 * 40;
    short* sh_l = sh_m + 48 * 40;
    float* Gs   = (float*)(sh_l + 48 * 40);    // [48][49]
    float* diag = Gs + 48 * 49;
    int b = blockIdx.x;
    int nt = (kn + 15) >> 4;
    int tasks = nt * nt;
    floatx4 acc[2] = {};
    int stage_elems = 384 * knt;
    const short* ksrc[3] = {kxh, kxm, kxl};
    short* kdst[3] = {sh_h, sh_m, sh_l};
    int karr[3], krr[3], kc4[3], kiters = 0;
    for (int e = tid; e < stage_elems; e += 512) {
      int a = e / 384, rem = e - a * 384;
      karr[kiters] = a; krr[kiters] = rem >> 3; kc4[kiters] = (rem & 7) * 4;
      ++kiters;
    }
    short4v pk[3];
    for (int it = 0; it < kiters; ++it)
      pk[it] = *(const short4v*)&ksrc[karr[it]][((size_t)(b * kn + krr[it])) * kKs + kc4[it]];
    for (int k0 = 0; k0 < kF32; k0 += 32) {
      for (int it = 0; it < kiters; ++it)
        *(short4v*)&kdst[karr[it]][krr[it] * 40 + kc4[it]] = pk[it];
      __syncthreads();
      int k1 = k0 + 32;
      if (k1 < kF32) {
        for (int it = 0; it < kiters; ++it)
          pk[it] = *(const short4v*)&ksrc[karr[it]][((size_t)(b * kn + krr[it])) * kKs + k1 + kc4[it]];
      }
#pragma unroll
      for (int ai = 0; ai < 2; ++ai) {
        int t = wave + ai * 8;
        if (t < tasks) {
          int ti = t / nt, tj = t - ti * nt;
          int ra = (ti * 16 + lm) * 40 + lk;
          int rb = (tj * 16 + lm) * 40 + lk;
          short8 ah = *(const short8*)&sh_h[ra];
          short8 am = *(const short8*)&sh_m[ra];
          short8 bh = *(const short8*)&sh_h[rb];
          short8 bm = *(const short8*)&sh_m[rb];
          floatx4 a = acc[ai];
          a = __builtin_amdgcn_mfma_f32_16x16x32_bf16(ah, bh, a, 0, 0, 0);
          a = __builtin_amdgcn_mfma_f32_16x16x32_bf16(ah, bm, a, 0, 0, 0);
          a = __builtin_amdgcn_mfma_f32_16x16x32_bf16(am, bh, a, 0, 0, 0);
          if (knt == 3) {
            short8 al = *(const short8*)&sh_l[ra];
            short8 bl = *(const short8*)&sh_l[rb];
            a = __builtin_amdgcn_mfma_f32_16x16x32_bf16(ah, bl, a, 0, 0, 0);
            a = __builtin_amdgcn_mfma_f32_16x16x32_bf16(al, bh, a, 0, 0, 0);
            a = __builtin_amdgcn_mfma_f32_16x16x32_bf16(am, bm, a, 0, 0, 0);
          }
          acc[ai] = a;
        }
      }
      __syncthreads();
    }
#pragma unroll
    for (int ai = 0; ai < 2; ++ai) {
      int t = wave + ai * 8;
      if (t < tasks) {
        int ti = t / nt, tj = t - ti * nt;
        int col = tj * 16 + lm;
        int rbase = ti * 16 + (lane >> 4) * 4;
#pragma unroll
        for (int r = 0; r < 4; ++r) Gs[(rbase + r) * 49 + col] = acc[ai][r];
      }
    }
    __syncthreads();
    if (tid < 48) diag[tid] = (tid < kn) ? Gs[tid * 49 + tid] : INFINITY;
    __syncthreads();
    for (int row = wave; row < kn; row += 8) {
      float gii = diag[row];
      float dj = (lane < kn) ? (gii + diag[lane] - 2.f * Gs[row * 49 + lane]) : INFINITY;
      int rank = 0;
      for (int j = 0; j < kn; ++j) {
        float djp = gii + diag[j] - 2.f * Gs[row * 49 + j];
        rank += (djp < dj || (djp == dj && j < lane)) ? 1 : 0;
      }
      if (lane < kn && rank < KNN_)
        idx[(size_t)(b * kn + row) * KNN_ + rank] = lane;
    }
  } else {
    // ---------------- GEMM path (8 waves: 2 row-groups x 4 col-groups) ----------------
    short* Ash = (short*)smem;
    short* Asm = Ash + 128 * 40;
    short* Asl = Asm + 128 * 40;
    short* Bsh = (short*)smem + gnt * 128 * 40;
    short* Bsm = Bsh + 128 * 40;
    short* Bsl = Bsm + 128 * 40;
    int gb = blockIdx.x - knnB;
    int gxB = (gN + 127) >> 7;
    int gx = gb % gxB;
    int rest = gb / gxB;
    int gy = rest % gyB;
    int gz = rest / gyB;
    const short* Asrc[3] = {Ah + (size_t)gz * Astride,
                            Am ? Am + (size_t)gz * Astride : nullptr,
                            Al ? Al + (size_t)gz * Astride : nullptr};
    const short* Bsrc[3] = {Wh, Wm, Wl};
    short* Adst[3] = {Ash, Asm, Asl};
    short* Bdst[3] = {Bsh, Bsm, Bsl};
    float* C = C0 + (size_t)gz * Cstride;
    int row0 = gy * 128, col0 = gx * 128;
    int wm = wave & 1, wn = wave >> 1;
    floatx4 acc[4][2] = {};
    int sr = tid >> 2, skc = (tid & 3) * 8;   // rem == tid at 512 threads
    short8 pA[3], pB[3];
#pragma unroll
    for (int a = 0; a < 3; ++a) {
      if (a < gnt) {
        pA[a] = *(const short8*)&Asrc[a][((size_t)(row0 + sr)) * gK + skc];
        pB[a] = *(const short8*)&Bsrc[a][((size_t)(col0 + sr)) * gK + skc];
      }
    }
    for (int k0 = 0; k0 < gK; k0 += 32) {
#pragma unroll
      for (int a = 0; a < 3; ++a) {
        if (a < gnt) {
          *(short8*)&Adst[a][sr * 40 + skc] = pA[a];
          *(short8*)&Bdst[a][sr * 40 + skc] = pB[a];
        }
      }
      __syncthreads();
      int k1 = k0 + 32;
      if (k1 < gK) {
#pragma unroll
        for (int a = 0; a < 3; ++a) {
          if (a < gnt) {
            pA[a] = *(const short8*)&Asrc[a][((size_t)(row0 + sr)) * gK + k1 + skc];
            pB[a] = *(const short8*)&Bsrc[a][((size_t)(col0 + sr)) * gK + k1 + skc];
          }
        }
      }
      short8 afh[4], afm[4], afl[4];
#pragma unroll
      for (int mi = 0; mi < 4; ++mi) {
        int ro = (wm * 64 + mi * 16 + lm) * 40 + lk;
        afh[mi] = *(const short8*)&Ash[ro];
        afm[mi] = *(const short8*)&Asm[ro];
        if (gnt == 3) afl[mi] = *(const short8*)&Asl[ro];
      }
#pragma unroll
      for (int ni = 0; ni < 2; ++ni) {
        int ro = (wn * 32 + ni * 16 + lm) * 40 + lk;
        short8 bfh = *(const short8*)&Bsh[ro];
        short8 bfm = *(const short8*)&Bsm[ro];
#pragma unroll
        for (int mi = 0; mi < 4; ++mi) {
          floatx4 a = acc[mi][ni];
          a = __builtin_amdgcn_mfma_f32_16x16x32_bf16(afh[mi], bfh, a, 0, 0, 0);
          a = __builtin_amdgcn_mfma_f32_16x16x32_bf16(afh[mi], bfm, a, 0, 0, 0);
          a = __builtin_amdgcn_mfma_f32_16x16x32_bf16(afm[mi], bfh, a, 0, 0, 0);
          if (gnt == 3) {
            short8 bfl = *(const short8*)&Bsl[ro];
            a = __builtin_amdgcn_mfma_f32_16x16x32_bf16(afh[mi], bfl, a, 0, 0, 0);
            a = __builtin_amdgcn_mfma_f32_16x16x32_bf16(afl[mi], bfh, a, 0, 0, 0);
            a = __builtin_amdgcn_mfma_f32_16x16x32_bf16(afm[mi], bfm, a, 0, 0, 0);
          }
          acc[mi][ni] = a;
        }
      }
      __syncthreads();
    }
    int lr = (lane >> 4) * 4;
#pragma unroll
    for (int mi = 0; mi < 4; ++mi)
#pragma unroll
      for (int ni = 0; ni < 2; ++ni) {
        int colg = col0 + wn * 32 + ni * 16 + lm;
        if (colg >= gN) continue;
#pragma unroll
        for (int r = 0; r < 4; ++r) {
          int rowg = row0 + wm * 64 + mi * 16 + lr + r;
          C[(size_t)rowg * gN + colg] = acc[mi][ni][r];
        }
      }
  }
}

// ------------- 2-term split MFMA GEMM w/ bias+relu+split-out (degree head) -------------
__global__ __launch_bounds__(256) void mfma_gemm_split_kernel(
    const short* __restrict__ Ah, const short* __restrict__ Al,
    const short* __restrict__ Wth, const short* __restrict__ Wtl,
    const float* __restrict__ bias,
    float* __restrict__ C, short* __restrict__ Ch, short* __restrict__ Cl,
    int M, int N, int K, int act) {
  __shared__ short Ash[128 * 40];
  __shared__ short Asl[128 * 40];
  __shared__ short Bsh[128 * 40];
  __shared__ short Bsl[128 * 40];
  int tid = threadIdx.x;
  int wave = tid >> 6, lane = tid & 63;
  int wm = wave & 1, wn = wave >> 1;
  int row0 = blockIdx.y * 128, col0 = blockIdx.x * 128;
  floatx4 acc[4][4] = {};
  int lm = lane & 15, lk = (lane >> 4) * 8;
  for (int k0 = 0; k0 < K; k0 += 32) {
    for (int c = tid; c < 512; c += 256) {
      int r = c >> 2, kc = (c & 3) * 8;
      int grow = row0 + r;
      short8 vh = {}, vl = {};
      if (grow < M) {
        vh = *(const short8*)&Ah[(size_t)grow * K + k0 + kc];
        vl = *(const short8*)&Al[(size_t)grow * K + k0 + kc];
      }
      *(short8*)&Ash[r * 40 + kc] = vh;
      *(short8*)&Asl[r * 40 + kc] = vl;
    }
    for (int c = tid; c < 512; c += 256) {
      int r = c >> 2, kc = (c & 3) * 8;
      int gn = col0 + r;
      short8 vh = {}, vl = {};
      if (gn < N) {
        vh = *(const short8*)&Wth[(size_t)gn * K + k0 + kc];
        vl = *(const short8*)&Wtl[(size_t)gn * K + k0 + kc];
      }
      *(short8*)&Bsh[r * 40 + kc] = vh;
      *(short8*)&Bsl[r * 40 + kc] = vl;
    }
    __syncthreads();
    short8 afh[4], afl[4], bfh[4], bfl[4];
#pragma unroll
    for (int mi = 0; mi < 4; ++mi) {
      int ro = (wm * 64 + mi * 16 + lm) * 40 + lk;
      afh[mi] = *(const short8*)&Ash[ro];
      afl[mi] = *(const short8*)&Asl[ro];
    }
#pragma unroll
    for (int ni = 0; ni < 4; ++ni) {
      int ro = (wn * 64 + ni * 16 + lm) * 40 + lk;
      bfh[ni] = *(const short8*)&Bsh[ro];
      bfl[ni] = *(const short8*)&Bsl[ro];
    }
#pragma unroll
    for (int mi = 0; mi < 4; ++mi)
#pragma unroll
      for (int ni = 0; ni < 4; ++ni) {
        acc[mi][ni] = __builtin_amdgcn_mfma_f32_16x16x32_bf16(afh[mi], bfh[ni], acc[mi][ni], 0, 0, 0);
        acc[mi][ni] = __builtin_amdgcn_mfma_f32_16x16x32_bf16(afh[mi], bfl[ni], acc[mi][ni], 0, 0, 0);
        acc[mi][ni] = __builtin_amdgcn_mfma_f32_16x16x32_bf16(afl[mi], bfh[ni], acc[mi][ni], 0, 0, 0);
      }
    __syncthreads();
  }
  int lr = (lane >> 4) * 4;
#pragma unroll
  for (int mi = 0; mi < 4; ++mi)
#pragma unroll
    for (int ni = 0; ni < 4; ++ni) {
      int colg = col0 + wn * 64 + ni * 16 + lm;
      if (colg >= N) continue;
      float bv = bias ? bias[colg] : 0.f;
#pragma unroll
      for (int r = 0; r < 4; ++r) {
        int rowg = row0 + wm * 64 + mi * 16 + lr + r;
        if (rowg >= M) continue;
        float v = acc[mi][ni][r] + bv;
        if (act == 1) v = fmaxf(v, 0.f);
        C[(size_t)rowg * N + colg] = v;
        if (Ch) {
          short hi = f2b(v);
          short lo = f2b(v - b2f(hi));
          Ch[(size_t)rowg * N + colg] = hi;
          Cl[(size_t)rowg * N + colg] = lo;
        }
      }
    }
}

// Thin GEMM (small M): one block per row.
__global__ __launch_bounds__(256) void rowgemm_kernel(
    const float* __restrict__ A, const float* __restrict__ W, const float* __restrict__ bias,
    float* __restrict__ C, int N, int K, int act) {
  __shared__ float a[512];
  int row = blockIdx.x;
  for (int k = threadIdx.x; k < K; k += 256) a[k] = A[(size_t)row * K + k];
  __syncthreads();
  for (int c = threadIdx.x; c < N; c += 256) {
    float s = 0.f;
    for (int k = 0; k < K; k += 4) {
      float4 av = *(const float4*)&a[k];
      s += av.x * W[(size_t)k * N + c];
      s += av.y * W[(size_t)(k + 1) * N + c];
      s += av.z * W[(size_t)(k + 2) * N + c];
      s += av.w * W[(size_t)(k + 3) * N + c];
    }
    float v = s + (bias ? bias[c] : 0.f);
    if (act == 1) v = fmaxf(v, 0.f);
    C[(size_t)row * N + c] = v;
  }
}

// one wave per output element (for very small M*N)
__global__ void wavedot_gemm_kernel(const float* __restrict__ A, const float* __restrict__ W,
                                    const float* __restrict__ bias, float* __restrict__ C,
                                    int M, int N, int K, int act) {
  int wid = (blockIdx.x * blockDim.x + threadIdx.x) >> 6;
  int lane = threadIdx.x & 63;
  if (wid >= M * N) return;
  int row = wid / N, col = wid - row * N;
  const float* ar = A + (size_t)row * K;
  float s = 0.f;
  for (int k = lane; k < K; k += 64) s += ar[k] * W[(size_t)k * N + col];
  for (int off = 32; off; off >>= 1) s += __shfl_down(s, off, 64);
  if (lane == 0) {
    float v = s + (bias ? bias[col] : 0.f);
    if (act == 1) v = fmaxf(v, 0.f);
    C[(size_t)row * N + col] = v;
  }
}

// edge agg over global rows (batched decoders: d = r / per); AB is (rows x 2Hc)
__global__ void edge_agg_kernel(const float* __restrict__ AB, const float* __restrict__ bias,
                                const int* __restrict__ idx, int n, int Hc, int act,
                                int rows, int per,
                                float* __restrict__ out,
                                short* __restrict__ outh, short* __restrict__ outm,
                                short* __restrict__ outl) {
  int t = blockIdx.x * blockDim.x + threadIdx.x;
  if (t >= rows * Hc) return;
  int r = t / Hc, h = t - r * Hc;
  int d = r / per, rloc = r - d * per;
  int b = rloc / n;
  int s2 = 2 * Hc;
  float av = AB[(size_t)r * s2 + h] + bias[h];
  const int* ir = idx + ((size_t)d * per + rloc) * KNN_;
  int base = d * per + b * n;
  float m = -INFINITY;
  for (int k = 0; k < KNN_; ++k) {
    float v = av + AB[(size_t)(base + ir[k]) * s2 + Hc + h];
    v = fmaxf(v, 0.f);
    m = fmaxf(m, v);
  }
  if (act == 2) m = tanhf(m);
  if (out) out[t] = m;
  if (outh) {
    short hh, mm, ll;
    f2b3(m, hh, mm, ll);
    outh[t] = hh; outm[t] = mm;
    if (outl) outl[t] = ll;
  }
}

// BN stats -> per-column scale/shift: norm(v) = relu(v*sc + sh)
__global__ void bn_stats_kernel(const float* __restrict__ xx, int M,
                                const float* __restrict__ g, const float* __restrict__ bb,
                                float* __restrict__ scsh) {
  int c = blockIdx.x;
  double s = 0.0, s2 = 0.0;
  for (int r = threadIdx.x; r < M; r += 256) {
    double v = (double)xx[(size_t)r * H_ + c];
    s += v; s2 += v * v;
  }
  __shared__ double sh[256], sh2[256];
  sh[threadIdx.x] = s; sh2[threadIdx.x] = s2;
  __syncthreads();
  for (int o = 128; o; o >>= 1) {
    if (threadIdx.x < o) { sh[threadIdx.x] += sh[threadIdx.x + o]; sh2[threadIdx.x] += sh2[threadIdx.x + o]; }
    __syncthreads();
  }
  if (threadIdx.x == 0) {
    double mean = sh[0] / M;
    double var = sh2[0] / M - mean * mean;
    float rstd = 1.f / sqrtf((float)var + 1e-5f);
    float sc = rstd * g[c];
    scsh[c] = sc;
    scsh[H_ + c] = bb[c] - (float)mean * sc;
  }
}

// BN-fused rowdot (wave per row): ys[r] = sum_k relu(t1*sc+sh) * pw
__global__ void bnrowdot_kernel(const float* __restrict__ t1, const float* __restrict__ scsh,
                                const float* __restrict__ pw, int M, float* __restrict__ ys) {
  int wid = (blockIdx.x * blockDim.x + threadIdx.x) >> 6;
  int lane = threadIdx.x & 63;
  if (wid >= M) return;
  const float* xr = t1 + (size_t)wid * H_;
  float s = 0.f;
  for (int k = lane; k < H_; k += 64) {
    float v = fmaxf(xr[k] * scsh[k] + scsh[H_ + k], 0.f);
    s += v * pw[k];
  }
  for (int off = 32; off; off >>= 1) s += __shfl_down(s, off, 64);
  if (lane == 0) ys[wid] = s;
}

// one wave per row: y[r] = dot(x[r,:K], w) [+bias] [relu]
__global__ void rowdot_kernel(const float* __restrict__ x, const float* __restrict__ w,
                              int M, int K, const float* __restrict__ bias, int act,
                              float* __restrict__ y) {
  int wid = (blockIdx.x * blockDim.x + threadIdx.x) >> 6;
  int lane = threadIdx.x & 63;
  if (wid >= M) return;
  const float* xr = x + (size_t)wid * K;
  float s = 0.f;
  for (int k = lane; k < K; k += 64) s += xr[k] * w[k];
  for (int off = 32; off; off >>= 1) s += __shfl_down(s, off, 64);
  if (lane == 0) {
    float v = s + (bias ? bias[0] : 0.f);
    if (act == 1) v = fmaxf(v, 0.f);
    y[wid] = v;
  }
}

// -------- sag select: gcn + rank-parallel topk --------
__global__ __launch_bounds__(256) void sag_select_kernel(
    const float* __restrict__ ysg,
    const float* __restrict__ adj_in, int n, int k,
    const float* __restrict__ pb,
    int* __restrict__ perm, float* __restrict__ tantg, int* __restrict__ locsg,
    float* __restrict__ adjp,
    const float* __restrict__ deg, const float* __restrict__ xdeg,
    float* __restrict__ gt, float* __restrict__ pred) {
  __shared__ float ys[40], dinv[40], scs[40];
  __shared__ int locs[40];
  int b = blockIdx.x;
  int i = threadIdx.x;
  if (i < n) {
    ys[i] = ysg[b * n + i];
    const float* ar = adj_in + ((size_t)b * n + i) * n;
    float sum = 1.f;
    for (int j = 0; j < n; ++j) sum += ar[j];
    dinv[i] = 1.f / sqrtf(sum);
  }
  __syncthreads();
  if (i < n) {
    const float* ar = adj_in + ((size_t)b * n + i) * n;
    float acc = 0.f;
    for (int j = 0; j < n; ++j) {
      float a = ar[j] + (i == j ? 1.f : 0.f);
      acc += a * dinv[j] * ys[j];
    }
    scs[i] = dinv[i] * acc + pb[0];
  }
  __syncthreads();
  if (i < n) {   // rank-based stable descending top-k (ties -> lowest index)
    float si = scs[i];
    int rank = 0;
    for (int j = 0; j < n; ++j) {
      float sj = scs[j];
      rank += (sj > si || (sj == si && j < i)) ? 1 : 0;
    }
    if (rank < k) {
      tantg[b * k + rank] = tanhf(si);
      locsg[b * k + rank] = i;
      locs[rank] = i;
      perm[b * k + rank] = b * n + i;
    }
  }
  __syncthreads();
  if (adjp) {
    for (int e = threadIdx.x; e < k * k; e += 256) {
      int t1i = e / k, t2i = e - t1i * k;
      adjp[(size_t)b * k * k + e] = adj_in[((size_t)b * n + locs[t1i]) * n + locs[t2i]];
    }
  }
  if (gt && threadIdx.x < k) {
    int p = b * n + locs[threadIdx.x];
    gt[b * k + threadIdx.x] = deg[p];
    pred[b * k + threadIdx.x] = xdeg[p];
  }
}

// -------- pool scatter: per-element gather+BN+tanh-scale -> xp triple + xout (h,m) --------
__global__ void pool_scatter_kernel(
    const float* __restrict__ t1, const float* __restrict__ scsh,
    const float* __restrict__ tantg, const int* __restrict__ locsg,
    const int* __restrict__ remap, int n, int k,
    short* __restrict__ xph, short* __restrict__ xpm, short* __restrict__ xpl,
    short* __restrict__ soh, short* __restrict__ som) {
  int t = blockIdx.x * blockDim.x + threadIdx.x;
  if (t >= B_ * k * H_) return;
  int r = t >> 8, hc = t & 255;
  int b = r / k, rr = r - b * k;
  int own = b * n + locsg[b * k + rr];
  float v = fmaxf(t1[(size_t)own * H_ + hc] * scsh[hc] + scsh[H_ + hc], 0.f) * tantg[b * k + rr];
  short hh, mm, ll;
  f2b3(v, hh, mm, ll);
  xph[t] = hh; xpm[t] = mm; xpl[t] = ll;
  int tgt = remap ? remap[own] : own;
  size_t so = (size_t)tgt * H_ + hc;
  soh[so] = hh; som[so] = mm;
}

// -------- readout: z[b] = [max_r xp, mean_r xp] from triple --------
__global__ void readout_kernel(const short* __restrict__ xph, const short* __restrict__ xpm,
                               const short* __restrict__ xpl, int k, int accum,
                               float* __restrict__ z) {
  int t = blockIdx.x * blockDim.x + threadIdx.x;
  if (t >= B_ * H_) return;
  int b = t >> 8, hc = t & 255;
  float mx = -INFINITY, sm = 0.f;
  for (int r = 0; r < k; ++r) {
    size_t o = ((size_t)(b * k + r)) * H_ + hc;
    float v = b2f(xph[o]) + b2f(xpm[o]) + b2f(xpl[o]);
    mx = fmaxf(mx, v);
    sm += v;
  }
  float* zb = z + (size_t)b * 2 * H_;
  float mean = sm / (float)k;
  if (accum) { zb[hc] += mx; zb[H_ + hc] += mean; }
  else       { zb[hc] = mx;  zb[H_ + hc] = mean; }
}

__global__ void gtpred_kernel(const float* __restrict__ deg, const float* __restrict__ xdeg,
                              const int* __restrict__ perm, int M,
                              float* __restrict__ gt, float* __restrict__ pred) {
  int t = blockIdx.x * blockDim.x + threadIdx.x;
  if (t >= M) return;
  int p = perm[t];
  gt[t] = deg[p];
  pred[t] = xdeg[p];
}

__global__ void softmax2_kernel(const float* __restrict__ logits, float* __restrict__ probs) {
  int b = blockIdx.x * blockDim.x + threadIdx.x;
  if (b >= B_) return;
  float a = logits[2 * b], c = logits[2 * b + 1];
  float m = fmaxf(a, c);
  float ea = expf(a - m), ec = expf(c - m);
  float inv = 1.f / (ea + ec);
  probs[2 * b] = ea * inv;
  probs[2 * b + 1] = ec * inv;
}

extern "C" void kernel_launch(void* const* d_in, const int* in_sizes, int n_in,
                              void* d_out, int out_size, void* d_ws, size_t ws_size,
                              hipStream_t stream) {
  auto in = [&](int i) { return (const float*)d_in[i]; };
  const float* x      = in(0);
  const float* adj    = in(1);
  const float* w_mlp1 = in(2);  const float* b_mlp1 = in(3);
  const float* w_mlp2 = in(4);  const float* b_mlp2 = in(5);
  const float* w_mlp3 = in(6);  const float* b_mlp3 = in(7);
  const float* w_mlp6 = in(8);  const float* b_mlp6 = in(9);
  const float* bn1_g = in(10);  const float* bn1_b = in(11);
  const float* bn2_g = in(12);  const float* bn2_b = in(13);
  const float* bn3_g = in(14);  const float* bn3_b = in(15);
  const float* p1_w = in(16);   const float* p1_b = in(17);
  const float* p2_w = in(18);   const float* p2_b = in(19);
  const float* p3_w = in(20);   const float* p3_b = in(21);
  const float* lin1_w = in(22); const float* lin1_b = in(23);
  const float* lin2_w = in(24); const float* lin2_b = in(25);
  const float* lin3_w = in(26); const float* lin3_b = in(27);
  const float* lin4_w = in(28); const float* lin4_b = in(29);
  const float* lin5_w = in(30); const float* lin5_b = in(31);
  const float* lin6_w = in(32); const float* lin6_b = in(33);

  float* out = (float*)d_out;
  float* out_probs = out;
  float* out_dec1  = out_probs + 256;            // 3 x 4992*39 contiguous
  float* out_gt1   = out_dec1 + 3 * 4992 * 39;
  float* out_pred1 = out_gt1 + 4096;
  float* out_gt2   = out_pred1 + 4096;
  float* out_pred2 = out_gt2 + 3328;
  float* out_gt3   = out_pred2 + 3328;
  float* out_pred3 = out_gt3 + 2688;

  char* base = (char*)d_ws;
  size_t off = 0;
  auto allocf = [&](size_t n) -> float* {
    float* p = (float*)(base + off);
    off += ((n * sizeof(float) + 255) & ~(size_t)255);
    return p;
  };
  auto alloci = [&](size_t n) -> int* {
    int* p = (int*)(base + off);
    off += ((n * sizeof(int) + 255) & ~(size_t)255);
    return p;
  };
  auto allocs = [&](size_t n) -> short* {
    short* p = (short*)(base + off);
    off += ((n * sizeof(short) + 255) & ~(size_t)255);
    return p;
  };

  const size_t S = (size_t)4992 * 256;
  const size_t AB_S = (size_t)4992 * 512;
  const int SI = 4992 * KNN_;

  short* wt1h = allocs(512 * 64); short* wt1m = allocs(512 * 64); short* wt1l = allocs(512 * 64);
  short* wt2h = allocs(512 * 256); short* wt2m = allocs(512 * 256); short* wt2l = allocs(512 * 256);
  short* wt3h = allocs(512 * 256); short* wt3m = allocs(512 * 256); short* wt3l = allocs(512 * 256);
  short* wt6h = allocs(78 * 256);  short* wt6m = allocs(78 * 256);
  short* l4h = allocs(256 * 256);  short* l4m = allocs(256 * 256);
  short* l5h = allocs(128 * 256);  short* l5m = allocs(128 * 256);
  short* xsph = allocs(4992 * 64); short* xspm = allocs(4992 * 64); short* xspl = allocs(4992 * 64);
  float* deg  = allocf(4992);
  float* xdeg = allocf(4992);
  float* ysg  = allocf(4992);
  int* idxb = alloci(3 * SI);
  float* AB3 = allocf(3 * AB_S);
  float* trunk_t1 = allocf(S);
  float* scsh = allocf(512);
  float* tantg = allocf(4096);
  int* locsg = alloci(4096);
  short* xph = allocs((size_t)4096 * 256); short* xpm = allocs((size_t)4096 * 256); short* xpl = allocs((size_t)4096 * 256);
  size_t ms0 = off;
  short* xoutb_h = allocs(3 * S);
  short* xoutb_m = allocs(3 * S);
  size_t msz = off - ms0;
  short* t1b_h = allocs(3 * S);
  short* t1b_m = allocs(3 * S);
  float* adj1 = allocf(128 * 32 * 32);
  float* adj2 = allocf(128 * 26 * 26);
  int* perm1 = alloci(4096); int* perm2 = alloci(3328); int* perm3 = alloci(2688);
  float* z  = allocf(128 * 512);
  float* z1 = allocf(128 * 256);
  float* z2 = allocf(128 * 128);
  float* logits = allocf(256);
  if (off > ws_size) return;

  // t2b aliases xoutb (dead after decoder stage 1)
  short* t2b_h = xoutb_h; short* t2b_m = xoutb_m;

  const size_t LDS3 = 6 * 128 * 40 * sizeof(short);          // 61440 (>= knn 21.2KB)
  const size_t LDS2 = 4 * 128 * 40 * sizeof(short);          // 40960

  // ---- prep + zero scatter targets ----
  prep_kernel<<<dim3(1248, 8), 256, 0, stream>>>(
      w_mlp1, w_mlp2, w_mlp3, w_mlp6, lin4_w, lin5_w, x, adj,
      wt1h, wt1m, wt1l, wt2h, wt2m, wt2l, wt3h, wt3m, wt3l, wt6h, wt6m,
      l4h, l4m, l5h, l5m, xsph, xspm, xspl, deg);
  hipMemsetAsync(xoutb_h, 0, msz, stream);

  // ---- level 1: fused knn+gemm, then agg/bn/select/pool ----
  knn_gemm_kernel<<<B_ + 4 * 39, 512, LDS3, stream>>>(
      xsph, xspm, xspl, 3, 64, N_, 64, idxb, B_,
      xsph, xspm, xspl, 3, 64, wt1h, wt1m, wt1l, AB3, 4992, 512, 39, 0, 0);
  edge_agg_kernel<<<cdiv(4992 * 256, 256), 256, 0, stream>>>(AB3, b_mlp1, idxb, N_, 256, 0, 4992, 4992,
                                                             trunk_t1, nullptr, nullptr, nullptr);
  bn_stats_kernel<<<H_, 256, 0, stream>>>(trunk_t1, 4992, bn1_g, bn1_b, scsh);
  bnrowdot_kernel<<<cdiv(4992 * 64, 256), 256, 0, stream>>>(trunk_t1, scsh, p1_w, 4992, ysg);
  sag_select_kernel<<<B_, 256, 0, stream>>>(ysg, adj, N_, K1_, p1_b,
                                            perm1, tantg, locsg, adj1,
                                            nullptr, nullptr, nullptr, nullptr);
  pool_scatter_kernel<<<cdiv(B_ * K1_ * H_, 256), 256, 0, stream>>>(
      trunk_t1, scsh, tantg, locsg, nullptr, N_, K1_, xph, xpm, xpl, xoutb_h, xoutb_m);
  readout_kernel<<<cdiv(B_ * H_, 256), 256, 0, stream>>>(xph, xpm, xpl, K1_, 0, z);
  {  // degree head from x_out1
    dim3 g4(2, 39);
    mfma_gemm_split_kernel<<<g4, 256, 0, stream>>>(xoutb_h, xoutb_m, l4h, l4m, lin4_b,
                                                   trunk_t1, t1b_h, t1b_m, 4992, 256, 256, 1);
    dim3 g5(1, 39);
    mfma_gemm_split_kernel<<<g5, 256, 0, stream>>>(t1b_h, t1b_m, l5h, l5m, lin5_b,
                                                   AB3, nullptr, nullptr, 4992, 128, 256, 1);
  }
  rowdot_kernel<<<cdiv(4992 * 64, 256), 256, 0, stream>>>(AB3, lin6_w, 4992, 128, lin6_b, 1, xdeg);
  gtpred_kernel<<<cdiv(4096, 256), 256, 0, stream>>>(deg, xdeg, perm1, 4096, out_gt1, out_pred1);

  // ---- level 2 ----
  knn_gemm_kernel<<<B_ + 4 * 32, 512, LDS3, stream>>>(
      xph, xpm, xpl, 3, 256, K1_, 256, idxb, B_,
      xph, xpm, xpl, 3, 256, wt2h, wt2m, wt2l, AB3, 4096, 512, 32, 0, 0);
  edge_agg_kernel<<<cdiv(4096 * 256, 256), 256, 0, stream>>>(AB3, b_mlp2, idxb, K1_, 256, 0, 4096, 4096,
                                                             trunk_t1, nullptr, nullptr, nullptr);
  bn_stats_kernel<<<H_, 256, 0, stream>>>(trunk_t1, 4096, bn2_g, bn2_b, scsh);
  bnrowdot_kernel<<<cdiv(4096 * 64, 256), 256, 0, stream>>>(trunk_t1, scsh, p2_w, 4096, ysg);
  sag_select_kernel<<<B_, 256, 0, stream>>>(ysg, adj1, K1_, K2_, p2_b,
                                            perm2, tantg, locsg, adj2,
                                            deg, xdeg, out_gt2, out_pred2);
  pool_scatter_kernel<<<cdiv(B_ * K2_ * H_, 256), 256, 0, stream>>>(
      trunk_t1, scsh, tantg, locsg, perm1, K1_, K2_, xph, xpm, xpl, xoutb_h + S, xoutb_m + S);
  readout_kernel<<<cdiv(B_ * H_, 256), 256, 0, stream>>>(xph, xpm, xpl, K2_, 1, z);

  // ---- level 3 ----
  knn_gemm_kernel<<<B_ + 4 * 26, 512, LDS3, stream>>>(
      xph, xpm, xpl, 3, 256, K2_, 256, idxb, B_,
      xph, xpm, xpl, 3, 256, wt3h, wt3m, wt3l, AB3, 3328, 512, 26, 0, 0);
  edge_agg_kernel<<<cdiv(3328 * 256, 256), 256, 0, stream>>>(AB3, b_mlp3, idxb, K2_, 256, 0, 3328, 3328,
                                                             trunk_t1, nullptr, nullptr, nullptr);
  bn_stats_kernel<<<H_, 256, 0, stream>>>(trunk_t1, 3328, bn3_g, bn3_b, scsh);
  bnrowdot_kernel<<<cdiv(3328 * 64, 256), 256, 0, stream>>>(trunk_t1, scsh, p3_w, 3328, ysg);
  sag_select_kernel<<<B_, 256, 0, stream>>>(ysg, adj2, K2_, K3_, p3_b,
                                            perm3, tantg, locsg, nullptr,
                                            deg, xdeg, out_gt3, out_pred3);
  pool_scatter_kernel<<<cdiv(B_ * K3_ * H_, 256), 256, 0, stream>>>(
      trunk_t1, scsh, tantg, locsg, perm2, K2_, K3_, xph, xpm, xpl, xoutb_h + 2 * S, xoutb_m + 2 * S);
  readout_kernel<<<cdiv(B_ * H_, 256), 256, 0, stream>>>(xph, xpm, xpl, K3_, 1, z);

  // ---- classifier head ----
  rowgemm_kernel<<<128, 256, 0, stream>>>(z, lin1_w, lin1_b, z1, 256, 512, 1);
  rowgemm_kernel<<<128, 256, 0, stream>>>(z1, lin2_w, lin2_b, z2, 128, 256, 1);
  wavedot_gemm_kernel<<<cdiv(128 * 2 * 64, 256), 256, 0, stream>>>(z2, lin3_w, lin3_b, logits, 128, 2, 128, 0);
  softmax2_kernel<<<1, 128, 0, stream>>>(logits, out_probs);

  // ---- batched decoders (3 independent; fused knn+gemm per stage) ----
  // stage 1: wcat3, tanh
  knn_gemm_kernel<<<3 * B_ + 4 * 39 * 3, 512, LDS2, stream>>>(
      xoutb_h, xoutb_m, nullptr, 2, 256, N_, 256, idxb, 3 * B_,
      xoutb_h, xoutb_m, nullptr, 2, 256, wt3h, wt3m, nullptr, AB3, 4992, 512, 39, S, AB_S);
  edge_agg_kernel<<<cdiv(3 * 4992 * 256, 256), 256, 0, stream>>>(
      AB3, b_mlp3, idxb, N_, 256, 2, 3 * 4992, 4992, nullptr, t1b_h, t1b_m, nullptr);
  // stage 2: wcat2, tanh
  knn_gemm_kernel<<<3 * B_ + 4 * 39 * 3, 512, LDS2, stream>>>(
      t1b_h, t1b_m, nullptr, 2, 256, N_, 256, idxb, 3 * B_,
      t1b_h, t1b_m, nullptr, 2, 256, wt2h, wt2m, nullptr, AB3, 4992, 512, 39, S, AB_S);
  edge_agg_kernel<<<cdiv(3 * 4992 * 256, 256), 256, 0, stream>>>(
      AB3, b_mlp2, idxb, N_, 256, 2, 3 * 4992, 4992, nullptr, t2b_h, t2b_m, nullptr);
  // stage 3: wcat6, linear -> out_dec
  knn_gemm_kernel<<<3 * B_ + 1 * 39 * 3, 512, LDS2, stream>>>(
      t2b_h, t2b_m, nullptr, 2, 256, N_, 256, idxb, 3 * B_,
      t2b_h, t2b_m, nullptr, 2, 256, wt6h, wt6m, nullptr, AB3, 4992, 78, 39, S, (size_t)4992 * 78);
  edge_agg_kernel<<<cdiv(3 * 4992 * 39, 256), 256, 0, stream>>>(
      AB3, b_mlp6, idxb, N_, 39, 0, 3 * 4992, 4992, out_dec1, nullptr, nullptr, nullptr);
}

// Round 18
// 566.080 us; speedup vs baseline: 1.2638x; 1.2638x over previous
//
#include <hip/hip_runtime.h>
#include <cmath>

#define B_   128
#define N_   39
#define KNN_ 10
#define H_   256
#define K1_  32
#define K2_  26
#define K3_  21

static inline int cdiv(int a, int b) { return (a + b - 1) / b; }

typedef __attribute__((ext_vector_type(8))) short short8;
typedef __attribute__((ext_vector_type(4))) short short4v;
typedef __attribute__((ext_vector_type(4))) float floatx4;

__device__ inline short f2b(float f) {   // fp32 -> bf16 RNE
  unsigned u = __float_as_uint(f);
  u += 0x7fff + ((u >> 16) & 1);
  return (short)(u >> 16);
}
__device__ inline float b2f(short h) {
  return __uint_as_float(((unsigned)(unsigned short)h) << 16);
}
__device__ inline void f2b3(float v, short& h, short& m, short& l) {  // v ~= h+m+l (24 bits)
  h = f2b(v);
  float r1 = v - b2f(h);
  m = f2b(r1);
  l = f2b(r1 - b2f(m));
}

// ------------- one-shot prep: weights triple-split transposed + x split + degree -------------
__global__ void prep_kernel(
    const float* __restrict__ w1, const float* __restrict__ w2,
    const float* __restrict__ w3, const float* __restrict__ w6,
    const float* __restrict__ l4, const float* __restrict__ l5,
    const float* __restrict__ x, const float* __restrict__ adj,
    short* __restrict__ wt1h, short* __restrict__ wt1m, short* __restrict__ wt1l,
    short* __restrict__ wt2h, short* __restrict__ wt2m, short* __restrict__ wt2l,
    short* __restrict__ wt3h, short* __restrict__ wt3m, short* __restrict__ wt3l,
    short* __restrict__ wt6h, short* __restrict__ wt6m,
    short* __restrict__ l4h, short* __restrict__ l4m,
    short* __restrict__ l5h, short* __restrict__ l5m,
    short* __restrict__ xsph, short* __restrict__ xspm, short* __restrict__ xspl,
    float* __restrict__ deg) {
  int task = blockIdx.y;
  int t = blockIdx.x * 256 + threadIdx.x;
  if (task == 0) {            // wcat1 tripleT: [512][64], K=39 padded
    if (t >= 512 * 64) return;
    int nn = t >> 6, k = t & 63;
    float v = 0.f;
    if (k < 39) v = (nn < 256) ? w1[k * 256 + nn] - w1[(39 + k) * 256 + nn]
                               : w1[(39 + k) * 256 + (nn - 256)];
    short h, m, l; f2b3(v, h, m, l);
    wt1h[t] = h; wt1m[t] = m; wt1l[t] = l;
  } else if (task == 1) {     // wcat2 tripleT: [512][256]
    if (t >= 512 * 256) return;
    int nn = t >> 8, k = t & 255;
    float v = (nn < 256) ? w2[k * 256 + nn] - w2[(256 + k) * 256 + nn]
                         : w2[(256 + k) * 256 + (nn - 256)];
    short h, m, l; f2b3(v, h, m, l);
    wt2h[t] = h; wt2m[t] = m; wt2l[t] = l;
  } else if (task == 2) {     // wcat3 tripleT
    if (t >= 512 * 256) return;
    int nn = t >> 8, k = t & 255;
    float v = (nn < 256) ? w3[k * 256 + nn] - w3[(256 + k) * 256 + nn]
                         : w3[(256 + k) * 256 + (nn - 256)];
    short h, m, l; f2b3(v, h, m, l);
    wt3h[t] = h; wt3m[t] = m; wt3l[t] = l;
  } else if (task == 3) {     // wcat6 T (h,m): [78][256]
    if (t >= 78 * 256) return;
    int nn = t >> 8, k = t & 255;
    float v = (nn < 39) ? w6[k * 39 + nn] - w6[(256 + k) * 39 + nn]
                        : w6[(256 + k) * 39 + (nn - 39)];
    short h, m, l; f2b3(v, h, m, l);
    wt6h[t] = h; wt6m[t] = m;
  } else if (task == 4) {     // lin4 T (h,m): [256][256]
    if (t >= 256 * 256) return;
    int nn = t >> 8, k = t & 255;
    short h, m, l; f2b3(l4[k * 256 + nn], h, m, l);
    l4h[t] = h; l4m[t] = m;
  } else if (task == 5) {     // lin5 T (h,m): [128][256]
    if (t >= 128 * 256) return;
    int nn = t >> 8, k = t & 255;
    short h, m, l; f2b3(l5[k * 128 + nn], h, m, l);
    l5h[t] = h; l5m[t] = m;
  } else if (task == 6) {     // x split: [4992][64], F=39 padded
    if (t >= 4992 * 64) return;
    int r = t >> 6, k = t & 63;
    float v = (k < 39) ? x[r * 39 + k] : 0.f;
    short h, m, l; f2b3(v, h, m, l);
    xsph[t] = h; xspm[t] = m; xspl[t] = l;
  } else {                    // degree
    if (t >= B_ * N_) return;
    const float* row = adj + (size_t)t * N_;
    float s = 0.f;
    for (int j = 0; j < N_; ++j) s += row[j];
    deg[t] = s;
  }
}

// ======== fused KNN + GEMM (one dispatch; block role by blockIdx.x) ========
// knn: blocks [0, knnB): MFMA gram + rank-parallel KNN (per graph).
// gemm: blocks [knnB, ...): C = A·W^T, M%128==0; store guard on N. Both 512 thr.
// nterms selects 2-term (~2^-16) or 3-term (~2^-24) split; MFMA order fixed.
__global__ __launch_bounds__(512) void knn_gemm_kernel(
    const short* __restrict__ kxh, const short* __restrict__ kxm, const short* __restrict__ kxl,
    int knt, int kKs, int kn, int kF32, int* __restrict__ idx, int knnB,
    const short* __restrict__ Ah, const short* __restrict__ Am, const short* __restrict__ Al,
    int gnt, int gK,
    const short* __restrict__ Wh, const short* __restrict__ Wm, const short* __restrict__ Wl,
    float* __restrict__ C0, int gM, int gN, int gyB,
    size_t Astride, size_t Cstride) {
  extern __shared__ char smem[];
  int tid = threadIdx.x;
  int wave = tid >> 6, lane = tid & 63;
  int lm = lane & 15, lk = (lane >> 4) * 8;
  if ((int)blockIdx.x < knnB) {
    // ---------------- KNN path ----------------
    short* sh_h = (short*)smem;
    short* sh_m = sh_h + 48 * 40;
    short* sh_l = sh_m + 48 * 40;
    float* Gs   = (float*)(sh_l + 48 * 40);    // [48][49]
    float* diag = Gs + 48 * 49;
    int b = blockIdx.x;
    int nt = (kn + 15) >> 4;
    int tasks = nt * nt;
    floatx4 acc[2] = {};
    int stage_elems = 384 * knt;
    for (int k0 = 0; k0 < kF32; k0 += 32) {
      for (int e = tid; e < stage_elems; e += 512) {
        int a = e / 384, rem = e - a * 384;
        int r = rem >> 3, c4 = (rem & 7) * 4;
        const short* src = (a == 0) ? kxh : (a == 1) ? kxm : kxl;
        short* dst = (a == 0) ? sh_h : (a == 1) ? sh_m : sh_l;
        *(short4v*)&dst[r * 40 + c4] =
            *(const short4v*)&src[((size_t)(b * kn + r)) * kKs + k0 + c4];
      }
      __syncthreads();
#pragma unroll
      for (int ai = 0; ai < 2; ++ai) {
        int t = wave + ai * 8;
        if (t < tasks) {
          int ti = t / nt, tj = t - ti * nt;
          int ra = (ti * 16 + lm) * 40 + lk;
          int rb = (tj * 16 + lm) * 40 + lk;
          short8 ah = *(const short8*)&sh_h[ra];
          short8 am = *(const short8*)&sh_m[ra];
          short8 bh = *(const short8*)&sh_h[rb];
          short8 bm = *(const short8*)&sh_m[rb];
          floatx4 a = acc[ai];
          a = __builtin_amdgcn_mfma_f32_16x16x32_bf16(ah, bh, a, 0, 0, 0);
          a = __builtin_amdgcn_mfma_f32_16x16x32_bf16(ah, bm, a, 0, 0, 0);
          a = __builtin_amdgcn_mfma_f32_16x16x32_bf16(am, bh, a, 0, 0, 0);
          if (knt == 3) {
            short8 al = *(const short8*)&sh_l[ra];
            short8 bl = *(const short8*)&sh_l[rb];
            a = __builtin_amdgcn_mfma_f32_16x16x32_bf16(ah, bl, a, 0, 0, 0);
            a = __builtin_amdgcn_mfma_f32_16x16x32_bf16(al, bh, a, 0, 0, 0);
            a = __builtin_amdgcn_mfma_f32_16x16x32_bf16(am, bm, a, 0, 0, 0);
          }
          acc[ai] = a;
        }
      }
      __syncthreads();
    }
#pragma unroll
    for (int ai = 0; ai < 2; ++ai) {
      int t = wave + ai * 8;
      if (t < tasks) {
        int ti = t / nt, tj = t - ti * nt;
        int col = tj * 16 + lm;
        int rbase = ti * 16 + (lane >> 4) * 4;
#pragma unroll
        for (int r = 0; r < 4; ++r) Gs[(rbase + r) * 49 + col] = acc[ai][r];
      }
    }
    __syncthreads();
    if (tid < 48) diag[tid] = (tid < kn) ? Gs[tid * 49 + tid] : INFINITY;
    __syncthreads();
    for (int row = wave; row < kn; row += 8) {
      float gii = diag[row];
      float dj = (lane < kn) ? (gii + diag[lane] - 2.f * Gs[row * 49 + lane]) : INFINITY;
      int rank = 0;
      for (int j = 0; j < kn; ++j) {
        float djp = gii + diag[j] - 2.f * Gs[row * 49 + j];
        rank += (djp < dj || (djp == dj && j < lane)) ? 1 : 0;
      }
      if (lane < kn && rank < KNN_)
        idx[(size_t)(b * kn + row) * KNN_ + rank] = lane;
    }
  } else {
    // ---------------- GEMM path (8 waves: 2 row-groups x 4 col-groups) ----------------
    short* Ash = (short*)smem;
    short* Asm = Ash + 128 * 40;
    short* Asl = Asm + 128 * 40;
    short* Bsh = (short*)smem + gnt * 128 * 40;
    short* Bsm = Bsh + 128 * 40;
    short* Bsl = Bsm + 128 * 40;
    int gb = blockIdx.x - knnB;
    int gxB = (gN + 127) >> 7;
    int gx = gb % gxB;
    int rest = gb / gxB;
    int gy = rest % gyB;
    int gz = rest / gyB;
    const short* A_h = Ah + (size_t)gz * Astride;
    const short* A_m = Am ? Am + (size_t)gz * Astride : nullptr;
    const short* A_l = Al ? Al + (size_t)gz * Astride : nullptr;
    float* C = C0 + (size_t)gz * Cstride;
    int row0 = gy * 128, col0 = gx * 128;
    int wm = wave & 1, wn = wave >> 1;
    floatx4 acc[4][2] = {};
    for (int k0 = 0; k0 < gK; k0 += 32) {
      for (int e = tid; e < gnt * 512; e += 512) {
        int a = e >> 9, rem = e & 511;
        int r = rem >> 2, kc = (rem & 3) * 8;
        const short* src = (a == 0) ? A_h : (a == 1) ? A_m : A_l;
        short* dst = (a == 0) ? Ash : (a == 1) ? Asm : Asl;
        *(short8*)&dst[r * 40 + kc] = *(const short8*)&src[((size_t)(row0 + r)) * gK + k0 + kc];
      }
      for (int e = tid; e < gnt * 512; e += 512) {
        int a = e >> 9, rem = e & 511;
        int r = rem >> 2, kc = (rem & 3) * 8;
        const short* src = (a == 0) ? Wh : (a == 1) ? Wm : Wl;
        short* dst = (a == 0) ? Bsh : (a == 1) ? Bsm : Bsl;
        *(short8*)&dst[r * 40 + kc] = *(const short8*)&src[((size_t)(col0 + r)) * gK + k0 + kc];
      }
      __syncthreads();
      short8 afh[4], afm[4], afl[4];
#pragma unroll
      for (int mi = 0; mi < 4; ++mi) {
        int ro = (wm * 64 + mi * 16 + lm) * 40 + lk;
        afh[mi] = *(const short8*)&Ash[ro];
        afm[mi] = *(const short8*)&Asm[ro];
        if (gnt == 3) afl[mi] = *(const short8*)&Asl[ro];
      }
#pragma unroll
      for (int ni = 0; ni < 2; ++ni) {
        int ro = (wn * 32 + ni * 16 + lm) * 40 + lk;
        short8 bfh = *(const short8*)&Bsh[ro];
        short8 bfm = *(const short8*)&Bsm[ro];
#pragma unroll
        for (int mi = 0; mi < 4; ++mi) {
          floatx4 a = acc[mi][ni];
          a = __builtin_amdgcn_mfma_f32_16x16x32_bf16(afh[mi], bfh, a, 0, 0, 0);
          a = __builtin_amdgcn_mfma_f32_16x16x32_bf16(afh[mi], bfm, a, 0, 0, 0);
          a = __builtin_amdgcn_mfma_f32_16x16x32_bf16(afm[mi], bfh, a, 0, 0, 0);
          if (gnt == 3) {
            short8 bfl = *(const short8*)&Bsl[ro];
            a = __builtin_amdgcn_mfma_f32_16x16x32_bf16(afh[mi], bfl, a, 0, 0, 0);
            a = __builtin_amdgcn_mfma_f32_16x16x32_bf16(afl[mi], bfh, a, 0, 0, 0);
            a = __builtin_amdgcn_mfma_f32_16x16x32_bf16(afm[mi], bfm, a, 0, 0, 0);
          }
          acc[mi][ni] = a;
        }
      }
      __syncthreads();
    }
    int lr = (lane >> 4) * 4;
#pragma unroll
    for (int mi = 0; mi < 4; ++mi)
#pragma unroll
      for (int ni = 0; ni < 2; ++ni) {
        int colg = col0 + wn * 32 + ni * 16 + lm;
        if (colg >= gN) continue;
#pragma unroll
        for (int r = 0; r < 4; ++r) {
          int rowg = row0 + wm * 64 + mi * 16 + lr + r;
          C[(size_t)rowg * gN + colg] = acc[mi][ni][r];
        }
      }
  }
}

// ------------- 2-term split MFMA GEMM w/ bias+relu+split-out (degree head) -------------
__global__ __launch_bounds__(256) void mfma_gemm_split_kernel(
    const short* __restrict__ Ah, const short* __restrict__ Al,
    const short* __restrict__ Wth, const short* __restrict__ Wtl,
    const float* __restrict__ bias,
    float* __restrict__ C, short* __restrict__ Ch, short* __restrict__ Cl,
    int M, int N, int K, int act) {
  __shared__ short Ash[128 * 40];
  __shared__ short Asl[128 * 40];
  __shared__ short Bsh[128 * 40];
  __shared__ short Bsl[128 * 40];
  int tid = threadIdx.x;
  int wave = tid >> 6, lane = tid & 63;
  int wm = wave & 1, wn = wave >> 1;
  int row0 = blockIdx.y * 128, col0 = blockIdx.x * 128;
  floatx4 acc[4][4] = {};
  int lm = lane & 15, lk = (lane >> 4) * 8;
  for (int k0 = 0; k0 < K; k0 += 32) {
    for (int c = tid; c < 512; c += 256) {
      int r = c >> 2, kc = (c & 3) * 8;
      int grow = row0 + r;
      short8 vh = {}, vl = {};
      if (grow < M) {
        vh = *(const short8*)&Ah[(size_t)grow * K + k0 + kc];
        vl = *(const short8*)&Al[(size_t)grow * K + k0 + kc];
      }
      *(short8*)&Ash[r * 40 + kc] = vh;
      *(short8*)&Asl[r * 40 + kc] = vl;
    }
    for (int c = tid; c < 512; c += 256) {
      int r = c >> 2, kc = (c & 3) * 8;
      int gn = col0 + r;
      short8 vh = {}, vl = {};
      if (gn < N) {
        vh = *(const short8*)&Wth[(size_t)gn * K + k0 + kc];
        vl = *(const short8*)&Wtl[(size_t)gn * K + k0 + kc];
      }
      *(short8*)&Bsh[r * 40 + kc] = vh;
      *(short8*)&Bsl[r * 40 + kc] = vl;
    }
    __syncthreads();
    short8 afh[4], afl[4], bfh[4], bfl[4];
#pragma unroll
    for (int mi = 0; mi < 4; ++mi) {
      int ro = (wm * 64 + mi * 16 + lm) * 40 + lk;
      afh[mi] = *(const short8*)&Ash[ro];
      afl[mi] = *(const short8*)&Asl[ro];
    }
#pragma unroll
    for (int ni = 0; ni < 4; ++ni) {
      int ro = (wn * 64 + ni * 16 + lm) * 40 + lk;
      bfh[ni] = *(const short8*)&Bsh[ro];
      bfl[ni] = *(const short8*)&Bsl[ro];
    }
#pragma unroll
    for (int mi = 0; mi < 4; ++mi)
#pragma unroll
      for (int ni = 0; ni < 4; ++ni) {
        acc[mi][ni] = __builtin_amdgcn_mfma_f32_16x16x32_bf16(afh[mi], bfh[ni], acc[mi][ni], 0, 0, 0);
        acc[mi][ni] = __builtin_amdgcn_mfma_f32_16x16x32_bf16(afh[mi], bfl[ni], acc[mi][ni], 0, 0, 0);
        acc[mi][ni] = __builtin_amdgcn_mfma_f32_16x16x32_bf16(afl[mi], bfh[ni], acc[mi][ni], 0, 0, 0);
      }
    __syncthreads();
  }
  int lr = (lane >> 4) * 4;
#pragma unroll
  for (int mi = 0; mi < 4; ++mi)
#pragma unroll
    for (int ni = 0; ni < 4; ++ni) {
      int colg = col0 + wn * 64 + ni * 16 + lm;
      if (colg >= N) continue;
      float bv = bias ? bias[colg] : 0.f;
#pragma unroll
      for (int r = 0; r < 4; ++r) {
        int rowg = row0 + wm * 64 + mi * 16 + lr + r;
        if (rowg >= M) continue;
        float v = acc[mi][ni][r] + bv;
        if (act == 1) v = fmaxf(v, 0.f);
        C[(size_t)rowg * N + colg] = v;
        if (Ch) {
          short hi = f2b(v);
          short lo = f2b(v - b2f(hi));
          Ch[(size_t)rowg * N + colg] = hi;
          Cl[(size_t)rowg * N + colg] = lo;
        }
      }
    }
}

// Thin GEMM (small M): one block per row.
__global__ __launch_bounds__(256) void rowgemm_kernel(
    const float* __restrict__ A, const float* __restrict__ W, const float* __restrict__ bias,
    float* __restrict__ C, int N, int K, int act) {
  __shared__ float a[512];
  int row = blockIdx.x;
  for (int k = threadIdx.x; k < K; k += 256) a[k] = A[(size_t)row * K + k];
  __syncthreads();
  for (int c = threadIdx.x; c < N; c += 256) {
    float s = 0.f;
    for (int k = 0; k < K; k += 4) {
      float4 av = *(const float4*)&a[k];
      s += av.x * W[(size_t)k * N + c];
      s += av.y * W[(size_t)(k + 1) * N + c];
      s += av.z * W[(size_t)(k + 2) * N + c];
      s += av.w * W[(size_t)(k + 3) * N + c];
    }
    float v = s + (bias ? bias[c] : 0.f);
    if (act == 1) v = fmaxf(v, 0.f);
    C[(size_t)row * N + c] = v;
  }
}

// one wave per output element (for very small M*N)
__global__ void wavedot_gemm_kernel(const float* __restrict__ A, const float* __restrict__ W,
                                    const float* __restrict__ bias, float* __restrict__ C,
                                    int M, int N, int K, int act) {
  int wid = (blockIdx.x * blockDim.x + threadIdx.x) >> 6;
  int lane = threadIdx.x & 63;
  if (wid >= M * N) return;
  int row = wid / N, col = wid - row * N;
  const float* ar = A + (size_t)row * K;
  float s = 0.f;
  for (int k = lane; k < K; k += 64) s += ar[k] * W[(size_t)k * N + col];
  for (int off = 32; off; off >>= 1) s += __shfl_down(s, off, 64);
  if (lane == 0) {
    float v = s + (bias ? bias[col] : 0.f);
    if (act == 1) v = fmaxf(v, 0.f);
    C[(size_t)row * N + col] = v;
  }
}

// edge agg over global rows (batched decoders: d = r / per); AB is (rows x 2Hc)
__global__ void edge_agg_kernel(const float* __restrict__ AB, const float* __restrict__ bias,
                                const int* __restrict__ idx, int n, int Hc, int act,
                                int rows, int per,
                                float* __restrict__ out,
                                short* __restrict__ outh, short* __restrict__ outm,
                                short* __restrict__ outl) {
  int t = blockIdx.x * blockDim.x + threadIdx.x;
  if (t >= rows * Hc) return;
  int r = t / Hc, h = t - r * Hc;
  int d = r / per, rloc = r - d * per;
  int b = rloc / n;
  int s2 = 2 * Hc;
  float av = AB[(size_t)r * s2 + h] + bias[h];
  const int* ir = idx + ((size_t)d * per + rloc) * KNN_;
  int base = d * per + b * n;
  float m = -INFINITY;
  for (int k = 0; k < KNN_; ++k) {
    float v = av + AB[(size_t)(base + ir[k]) * s2 + Hc + h];
    v = fmaxf(v, 0.f);
    m = fmaxf(m, v);
  }
  if (act == 2) m = tanhf(m);
  if (out) out[t] = m;
  if (outh) {
    short hh, mm, ll;
    f2b3(m, hh, mm, ll);
    outh[t] = hh; outm[t] = mm;
    if (outl) outl[t] = ll;
  }
}

// BN stats -> per-column scale/shift: norm(v) = relu(v*sc + sh)
__global__ void bn_stats_kernel(const float* __restrict__ xx, int M,
                                const float* __restrict__ g, const float* __restrict__ bb,
                                float* __restrict__ scsh) {
  int c = blockIdx.x;
  double s = 0.0, s2 = 0.0;
  for (int r = threadIdx.x; r < M; r += 256) {
    double v = (double)xx[(size_t)r * H_ + c];
    s += v; s2 += v * v;
  }
  __shared__ double sh[256], sh2[256];
  sh[threadIdx.x] = s; sh2[threadIdx.x] = s2;
  __syncthreads();
  for (int o = 128; o; o >>= 1) {
    if (threadIdx.x < o) { sh[threadIdx.x] += sh[threadIdx.x + o]; sh2[threadIdx.x] += sh2[threadIdx.x + o]; }
    __syncthreads();
  }
  if (threadIdx.x == 0) {
    double mean = sh[0] / M;
    double var = sh2[0] / M - mean * mean;
    float rstd = 1.f / sqrtf((float)var + 1e-5f);
    float sc = rstd * g[c];
    scsh[c] = sc;
    scsh[H_ + c] = bb[c] - (float)mean * sc;
  }
}

// BN-fused rowdot (wave per row): ys[r] = sum_k relu(t1*sc+sh) * pw
__global__ void bnrowdot_kernel(const float* __restrict__ t1, const float* __restrict__ scsh,
                                const float* __restrict__ pw, int M, float* __restrict__ ys) {
  int wid = (blockIdx.x * blockDim.x + threadIdx.x) >> 6;
  int lane = threadIdx.x & 63;
  if (wid >= M) return;
  const float* xr = t1 + (size_t)wid * H_;
  float s = 0.f;
  for (int k = lane; k < H_; k += 64) {
    float v = fmaxf(xr[k] * scsh[k] + scsh[H_ + k], 0.f);
    s += v * pw[k];
  }
  for (int off = 32; off; off >>= 1) s += __shfl_down(s, off, 64);
  if (lane == 0) ys[wid] = s;
}

// one wave per row: y[r] = dot(x[r,:K], w) [+bias] [relu]
__global__ void rowdot_kernel(const float* __restrict__ x, const float* __restrict__ w,
                              int M, int K, const float* __restrict__ bias, int act,
                              float* __restrict__ y) {
  int wid = (blockIdx.x * blockDim.x + threadIdx.x) >> 6;
  int lane = threadIdx.x & 63;
  if (wid >= M) return;
  const float* xr = x + (size_t)wid * K;
  float s = 0.f;
  for (int k = lane; k < K; k += 64) s += xr[k] * w[k];
  for (int off = 32; off; off >>= 1) s += __shfl_down(s, off, 64);
  if (lane == 0) {
    float v = s + (bias ? bias[0] : 0.f);
    if (act == 1) v = fmaxf(v, 0.f);
    y[wid] = v;
  }
}

// -------- sag select: gcn + rank-parallel topk --------
__global__ __launch_bounds__(256) void sag_select_kernel(
    const float* __restrict__ ysg,
    const float* __restrict__ adj_in, int n, int k,
    const float* __restrict__ pb,
    int* __restrict__ perm, float* __restrict__ tantg, int* __restrict__ locsg,
    float* __restrict__ adjp,
    const float* __restrict__ deg, const float* __restrict__ xdeg,
    float* __restrict__ gt, float* __restrict__ pred) {
  __shared__ float ys[40], dinv[40], scs[40];
  __shared__ int locs[40];
  int b = blockIdx.x;
  int i = threadIdx.x;
  if (i < n) {
    ys[i] = ysg[b * n + i];
    const float* ar = adj_in + ((size_t)b * n + i) * n;
    float sum = 1.f;
    for (int j = 0; j < n; ++j) sum += ar[j];
    dinv[i] = 1.f / sqrtf(sum);
  }
  __syncthreads();
  if (i < n) {
    const float* ar = adj_in + ((size_t)b * n + i) * n;
    float acc = 0.f;
    for (int j = 0; j < n; ++j) {
      float a = ar[j] + (i == j ? 1.f : 0.f);
      acc += a * dinv[j] * ys[j];
    }
    scs[i] = dinv[i] * acc + pb[0];
  }
  __syncthreads();
  if (i < n) {   // rank-based stable descending top-k (ties -> lowest index)
    float si = scs[i];
    int rank = 0;
    for (int j = 0; j < n; ++j) {
      float sj = scs[j];
      rank += (sj > si || (sj == si && j < i)) ? 1 : 0;
    }
    if (rank < k) {
      tantg[b * k + rank] = tanhf(si);
      locsg[b * k + rank] = i;
      locs[rank] = i;
      perm[b * k + rank] = b * n + i;
    }
  }
  __syncthreads();
  if (adjp) {
    for (int e = threadIdx.x; e < k * k; e += 256) {
      int t1i = e / k, t2i = e - t1i * k;
      adjp[(size_t)b * k * k + e] = adj_in[((size_t)b * n + locs[t1i]) * n + locs[t2i]];
    }
  }
  if (gt && threadIdx.x < k) {
    int p = b * n + locs[threadIdx.x];
    gt[b * k + threadIdx.x] = deg[p];
    pred[b * k + threadIdx.x] = xdeg[p];
  }
}

// -------- pool scatter: per-element gather+BN+tanh-scale -> xp triple + xout (h,m) --------
__global__ void pool_scatter_kernel(
    const float* __restrict__ t1, const float* __restrict__ scsh,
    const float* __restrict__ tantg, const int* __restrict__ locsg,
    const int* __restrict__ remap, int n, int k,
    short* __restrict__ xph, short* __restrict__ xpm, short* __restrict__ xpl,
    short* __restrict__ soh, short* __restrict__ som) {
  int t = blockIdx.x * blockDim.x + threadIdx.x;
  if (t >= B_ * k * H_) return;
  int r = t >> 8, hc = t & 255;
  int b = r / k, rr = r - b * k;
  int own = b * n + locsg[b * k + rr];
  float v = fmaxf(t1[(size_t)own * H_ + hc] * scsh[hc] + scsh[H_ + hc], 0.f) * tantg[b * k + rr];
  short hh, mm, ll;
  f2b3(v, hh, mm, ll);
  xph[t] = hh; xpm[t] = mm; xpl[t] = ll;
  int tgt = remap ? remap[own] : own;
  size_t so = (size_t)tgt * H_ + hc;
  soh[so] = hh; som[so] = mm;
}

// -------- readout: z[b] = [max_r xp, mean_r xp] from triple --------
__global__ void readout_kernel(const short* __restrict__ xph, const short* __restrict__ xpm,
                               const short* __restrict__ xpl, int k, int accum,
                               float* __restrict__ z) {
  int t = blockIdx.x * blockDim.x + threadIdx.x;
  if (t >= B_ * H_) return;
  int b = t >> 8, hc = t & 255;
  float mx = -INFINITY, sm = 0.f;
  for (int r = 0; r < k; ++r) {
    size_t o = ((size_t)(b * k + r)) * H_ + hc;
    float v = b2f(xph[o]) + b2f(xpm[o]) + b2f(xpl[o]);
    mx = fmaxf(mx, v);
    sm += v;
  }
  float* zb = z + (size_t)b * 2 * H_;
  float mean = sm / (float)k;
  if (accum) { zb[hc] += mx; zb[H_ + hc] += mean; }
  else       { zb[hc] = mx;  zb[H_ + hc] = mean; }
}

__global__ void gtpred_kernel(const float* __restrict__ deg, const float* __restrict__ xdeg,
                              const int* __restrict__ perm, int M,
                              float* __restrict__ gt, float* __restrict__ pred) {
  int t = blockIdx.x * blockDim.x + threadIdx.x;
  if (t >= M) return;
  int p = perm[t];
  gt[t] = deg[p];
  pred[t] = xdeg[p];
}

__global__ void softmax2_kernel(const float* __restrict__ logits, float* __restrict__ probs) {
  int b = blockIdx.x * blockDim.x + threadIdx.x;
  if (b >= B_) return;
  float a = logits[2 * b], c = logits[2 * b + 1];
  float m = fmaxf(a, c);
  float ea = expf(a - m), ec = expf(c - m);
  float inv = 1.f / (ea + ec);
  probs[2 * b] = ea * inv;
  probs[2 * b + 1] = ec * inv;
}

extern "C" void kernel_launch(void* const* d_in, const int* in_sizes, int n_in,
                              void* d_out, int out_size, void* d_ws, size_t ws_size,
                              hipStream_t stream) {
  auto in = [&](int i) { return (const float*)d_in[i]; };
  const float* x      = in(0);
  const float* adj    = in(1);
  const float* w_mlp1 = in(2);  const float* b_mlp1 = in(3);
  const float* w_mlp2 = in(4);  const float* b_mlp2 = in(5);
  const float* w_mlp3 = in(6);  const float* b_mlp3 = in(7);
  const float* w_mlp6 = in(8);  const float* b_mlp6 = in(9);
  const float* bn1_g = in(10);  const float* bn1_b = in(11);
  const float* bn2_g = in(12);  const float* bn2_b = in(13);
  const float* bn3_g = in(14);  const float* bn3_b = in(15);
  const float* p1_w = in(16);   const float* p1_b = in(17);
  const float* p2_w = in(18);   const float* p2_b = in(19);
  const float* p3_w = in(20);   const float* p3_b = in(21);
  const float* lin1_w = in(22); const float* lin1_b = in(23);
  const float* lin2_w = in(24); const float* lin2_b = in(25);
  const float* lin3_w = in(26); const float* lin3_b = in(27);
  const float* lin4_w = in(28); const float* lin4_b = in(29);
  const float* lin5_w = in(30); const float* lin5_b = in(31);
  const float* lin6_w = in(32); const float* lin6_b = in(33);

  float* out = (float*)d_out;
  float* out_probs = out;
  float* out_dec1  = out_probs + 256;            // 3 x 4992*39 contiguous
  float* out_gt1   = out_dec1 + 3 * 4992 * 39;
  float* out_pred1 = out_gt1 + 4096;
  float* out_gt2   = out_pred1 + 4096;
  float* out_pred2 = out_gt2 + 3328;
  float* out_gt3   = out_pred2 + 3328;
  float* out_pred3 = out_gt3 + 2688;

  char* base = (char*)d_ws;
  size_t off = 0;
  auto allocf = [&](size_t n) -> float* {
    float* p = (float*)(base + off);
    off += ((n * sizeof(float) + 255) & ~(size_t)255);
    return p;
  };
  auto alloci = [&](size_t n) -> int* {
    int* p = (int*)(base + off);
    off += ((n * sizeof(int) + 255) & ~(size_t)255);
    return p;
  };
  auto allocs = [&](size_t n) -> short* {
    short* p = (short*)(base + off);
    off += ((n * sizeof(short) + 255) & ~(size_t)255);
    return p;
  };

  const size_t S = (size_t)4992 * 256;
  const size_t AB_S = (size_t)4992 * 512;
  const int SI = 4992 * KNN_;

  short* wt1h = allocs(512 * 64); short* wt1m = allocs(512 * 64); short* wt1l = allocs(512 * 64);
  short* wt2h = allocs(512 * 256); short* wt2m = allocs(512 * 256); short* wt2l = allocs(512 * 256);
  short* wt3h = allocs(512 * 256); short* wt3m = allocs(512 * 256); short* wt3l = allocs(512 * 256);
  short* wt6h = allocs(78 * 256);  short* wt6m = allocs(78 * 256);
  short* l4h = allocs(256 * 256);  short* l4m = allocs(256 * 256);
  short* l5h = allocs(128 * 256);  short* l5m = allocs(128 * 256);
  short* xsph = allocs(4992 * 64); short* xspm = allocs(4992 * 64); short* xspl = allocs(4992 * 64);
  float* deg  = allocf(4992);
  float* xdeg = allocf(4992);
  float* ysg  = allocf(4992);
  int* idxb = alloci(3 * SI);
  float* AB3 = allocf(3 * AB_S);
  float* trunk_t1 = allocf(S);
  float* scsh = allocf(512);
  float* tantg = allocf(4096);
  int* locsg = alloci(4096);
  short* xph = allocs((size_t)4096 * 256); short* xpm = allocs((size_t)4096 * 256); short* xpl = allocs((size_t)4096 * 256);
  size_t ms0 = off;
  short* xoutb_h = allocs(3 * S);
  short* xoutb_m = allocs(3 * S);
  size_t msz = off - ms0;
  short* t1b_h = allocs(3 * S);
  short* t1b_m = allocs(3 * S);
  float* adj1 = allocf(128 * 32 * 32);
  float* adj2 = allocf(128 * 26 * 26);
  int* perm1 = alloci(4096); int* perm2 = alloci(3328); int* perm3 = alloci(2688);
  float* z  = allocf(128 * 512);
  float* z1 = allocf(128 * 256);
  float* z2 = allocf(128 * 128);
  float* logits = allocf(256);
  if (off > ws_size) return;

  // t2b aliases xoutb (dead after decoder stage 1)
  short* t2b_h = xoutb_h; short* t2b_m = xoutb_m;

  const size_t LDS3 = 6 * 128 * 40 * sizeof(short);          // 61440 (>= knn 21.2KB)
  const size_t LDS2 = 4 * 128 * 40 * sizeof(short);          // 40960

  // ---- prep + zero scatter targets ----
  prep_kernel<<<dim3(1248, 8), 256, 0, stream>>>(
      w_mlp1, w_mlp2, w_mlp3, w_mlp6, lin4_w, lin5_w, x, adj,
      wt1h, wt1m, wt1l, wt2h, wt2m, wt2l, wt3h, wt3m, wt3l, wt6h, wt6m,
      l4h, l4m, l5h, l5m, xsph, xspm, xspl, deg);
  hipMemsetAsync(xoutb_h, 0, msz, stream);

  // ---- level 1: fused knn+gemm, then agg/bn/select/pool ----
  knn_gemm_kernel<<<B_ + 4 * 39, 512, LDS3, stream>>>(
      xsph, xspm, xspl, 3, 64, N_, 64, idxb, B_,
      xsph, xspm, xspl, 3, 64, wt1h, wt1m, wt1l, AB3, 4992, 512, 39, 0, 0);
  edge_agg_kernel<<<cdiv(4992 * 256, 256), 256, 0, stream>>>(AB3, b_mlp1, idxb, N_, 256, 0, 4992, 4992,
                                                             trunk_t1, nullptr, nullptr, nullptr);
  bn_stats_kernel<<<H_, 256, 0, stream>>>(trunk_t1, 4992, bn1_g, bn1_b, scsh);
  bnrowdot_kernel<<<cdiv(4992 * 64, 256), 256, 0, stream>>>(trunk_t1, scsh, p1_w, 4992, ysg);
  sag_select_kernel<<<B_, 256, 0, stream>>>(ysg, adj, N_, K1_, p1_b,
                                            perm1, tantg, locsg, adj1,
                                            nullptr, nullptr, nullptr, nullptr);
  pool_scatter_kernel<<<cdiv(B_ * K1_ * H_, 256), 256, 0, stream>>>(
      trunk_t1, scsh, tantg, locsg, nullptr, N_, K1_, xph, xpm, xpl, xoutb_h, xoutb_m);
  readout_kernel<<<cdiv(B_ * H_, 256), 256, 0, stream>>>(xph, xpm, xpl, K1_, 0, z);
  {  // degree head from x_out1
    dim3 g4(2, 39);
    mfma_gemm_split_kernel<<<g4, 256, 0, stream>>>(xoutb_h, xoutb_m, l4h, l4m, lin4_b,
                                                   trunk_t1, t1b_h, t1b_m, 4992, 256, 256, 1);
    dim3 g5(1, 39);
    mfma_gemm_split_kernel<<<g5, 256, 0, stream>>>(t1b_h, t1b_m, l5h, l5m, lin5_b,
                                                   AB3, nullptr, nullptr, 4992, 128, 256, 1);
  }
  rowdot_kernel<<<cdiv(4992 * 64, 256), 256, 0, stream>>>(AB3, lin6_w, 4992, 128, lin6_b, 1, xdeg);
  gtpred_kernel<<<cdiv(4096, 256), 256, 0, stream>>>(deg, xdeg, perm1, 4096, out_gt1, out_pred1);

  // ---- level 2 ----
  knn_gemm_kernel<<<B_ + 4 * 32, 512, LDS3, stream>>>(
      xph, xpm, xpl, 3, 256, K1_, 256, idxb, B_,
      xph, xpm, xpl, 3, 256, wt2h, wt2m, wt2l, AB3, 4096, 512, 32, 0, 0);
  edge_agg_kernel<<<cdiv(4096 * 256, 256), 256, 0, stream>>>(AB3, b_mlp2, idxb, K1_, 256, 0, 4096, 4096,
                                                             trunk_t1, nullptr, nullptr, nullptr);
  bn_stats_kernel<<<H_, 256, 0, stream>>>(trunk_t1, 4096, bn2_g, bn2_b, scsh);
  bnrowdot_kernel<<<cdiv(4096 * 64, 256), 256, 0, stream>>>(trunk_t1, scsh, p2_w, 4096, ysg);
  sag_select_kernel<<<B_, 256, 0, stream>>>(ysg, adj1, K1_, K2_, p2_b,
                                            perm2, tantg, locsg, adj2,
                                            deg, xdeg, out_gt2, out_pred2);
  pool_scatter_kernel<<<cdiv(B_ * K2_ * H_, 256), 256, 0, stream>>>(
      trunk_t1, scsh, tantg, locsg, perm1, K1_, K2_, xph, xpm, xpl, xoutb_h + S, xoutb_m + S);
  readout_kernel<<<cdiv(B_ * H_, 256), 256, 0, stream>>>(xph, xpm, xpl, K2_, 1, z);

  // ---- level 3 ----
  knn_gemm_kernel<<<B_ + 4 * 26, 512, LDS3, stream>>>(
      xph, xpm, xpl, 3, 256, K2_, 256, idxb, B_,
      xph, xpm, xpl, 3, 256, wt3h, wt3m, wt3l, AB3, 3328, 512, 26, 0, 0);
  edge_agg_kernel<<<cdiv(3328 * 256, 256), 256, 0, stream>>>(AB3, b_mlp3, idxb, K2_, 256, 0, 3328, 3328,
                                                             trunk_t1, nullptr, nullptr, nullptr);
  bn_stats_kernel<<<H_, 256, 0, stream>>>(trunk_t1, 3328, bn3_g, bn3_b, scsh);
  bnrowdot_kernel<<<cdiv(3328 * 64, 256), 256, 0, stream>>>(trunk_t1, scsh, p3_w, 3328, ysg);
  sag_select_kernel<<<B_, 256, 0, stream>>>(ysg, adj2, K2_, K3_, p3_b,
                                            perm3, tantg, locsg, nullptr,
                                            deg, xdeg, out_gt3, out_pred3);
  pool_scatter_kernel<<<cdiv(B_ * K3_ * H_, 256), 256, 0, stream>>>(
      trunk_t1, scsh, tantg, locsg, perm2, K2_, K3_, xph, xpm, xpl, xoutb_h + 2 * S, xoutb_m + 2 * S);
  readout_kernel<<<cdiv(B_ * H_, 256), 256, 0, stream>>>(xph, xpm, xpl, K3_, 1, z);

  // ---- classifier head ----
  rowgemm_kernel<<<128, 256, 0, stream>>>(z, lin1_w, lin1_b, z1, 256, 512, 1);
  rowgemm_kernel<<<128, 256, 0, stream>>>(z1, lin2_w, lin2_b, z2, 128, 256, 1);
  wavedot_gemm_kernel<<<cdiv(128 * 2 * 64, 256), 256, 0, stream>>>(z2, lin3_w, lin3_b, logits, 128, 2, 128, 0);
  softmax2_kernel<<<1, 128, 0, stream>>>(logits, out_probs);

  // ---- batched decoders (3 independent; fused knn+gemm per stage) ----
  // stage 1: wcat3, tanh
  knn_gemm_kernel<<<3 * B_ + 4 * 39 * 3, 512, LDS2, stream>>>(
      xoutb_h, xoutb_m, nullptr, 2, 256, N_, 256, idxb, 3 * B_,
      xoutb_h, xoutb_m, nullptr, 2, 256, wt3h, wt3m, nullptr, AB3, 4992, 512, 39, S, AB_S);
  edge_agg_kernel<<<cdiv(3 * 4992 * 256, 256), 256, 0, stream>>>(
      AB3, b_mlp3, idxb, N_, 256, 2, 3 * 4992, 4992, nullptr, t1b_h, t1b_m, nullptr);
  // stage 2: wcat2, tanh
  knn_gemm_kernel<<<3 * B_ + 4 * 39 * 3, 512, LDS2, stream>>>(
      t1b_h, t1b_m, nullptr, 2, 256, N_, 256, idxb, 3 * B_,
      t1b_h, t1b_m, nullptr, 2, 256, wt2h, wt2m, nullptr, AB3, 4992, 512, 39, S, AB_S);
  edge_agg_kernel<<<cdiv(3 * 4992 * 256, 256), 256, 0, stream>>>(
      AB3, b_mlp2, idxb, N_, 256, 2, 3 * 4992, 4992, nullptr, t2b_h, t2b_m, nullptr);
  // stage 3: wcat6, linear -> out_dec
  knn_gemm_kernel<<<3 * B_ + 1 * 39 * 3, 512, LDS2, stream>>>(
      t2b_h, t2b_m, nullptr, 2, 256, N_, 256, idxb, 3 * B_,
      t2b_h, t2b_m, nullptr, 2, 256, wt6h, wt6m, nullptr, AB3, 4992, 78, 39, S, (size_t)4992 * 78);
  edge_agg_kernel<<<cdiv(3 * 4992 * 39, 256), 256, 0, stream>>>(
      AB3, b_mlp6, idxb, N_, 39, 0, 3 * 4992, 4992, out_dec1, nullptr, nullptr, nullptr);
}